// Round 3
// baseline (184.582 us; speedup 1.0000x reference)
//
#include <hip/hip_runtime.h>

#define EPS 1e-4f
#define NAXIS 8
#define NKNOTS 16      // interior knots; 18 total x-positions, 17 segments
#define NSEG 17
// per-batch workspace layout (floats), stride 384:
//  [0..24)    pinv[a*3+c]
//  [24..48)   uA[a*3+c]  = A[c][a] * invdx[a]   (projection straight into u-space)
//  [48..56)   uoff[a]    = -mins[a] * invdx[a]
//  [56..64)   pad
//  [64..336)  seg[a*17+s] as float2 {dy, icept}: est = dy*u + icept
#define WS_STRIDE 384
#define TILES 4                 // tiles per block (software-pipelined)
#define PXB (TILES * 1024)      // floats per block per color stream

typedef float fv4 __attribute__((ext_vector_type(4)));   // native vector: OK for nontemporal builtins

__global__ void spline_prep(const float* __restrict__ ys,
                            const float* __restrict__ A,
                            float* __restrict__ ws) {
    const int b = blockIdx.x;
    const float* Ab  = A  + (size_t)b * 3 * NAXIS;     // A[c*8+a]
    const float* ysb = ys + (size_t)b * NAXIS * NKNOTS;
    float* w = ws + (size_t)b * WS_STRIDE;
    __shared__ double Ginv[9];
    const int tid = threadIdx.x;

    if (tid == 0) {
        // G = A A^T (3x3, symmetric), fp64 for safety
        double G[9];
        for (int i = 0; i < 3; ++i)
            for (int j = 0; j < 3; ++j) {
                double s = 0.0;
                for (int a = 0; a < NAXIS; ++a)
                    s += (double)Ab[i * NAXIS + a] * (double)Ab[j * NAXIS + a];
                G[i * 3 + j] = s;
            }
        const double g00 = G[0], g01 = G[1], g02 = G[2];
        const double g11 = G[4], g12 = G[5], g22 = G[8];
        const double det = g00 * (g11 * g22 - g12 * g12)
                         - g01 * (g01 * g22 - g12 * g02)
                         + g02 * (g01 * g12 - g11 * g02);
        const double inv = 1.0 / det;
        Ginv[0] = (g11 * g22 - g12 * g12) * inv;
        Ginv[1] = (g02 * g12 - g01 * g22) * inv;
        Ginv[2] = (g01 * g12 - g02 * g11) * inv;
        Ginv[3] = Ginv[1];
        Ginv[4] = (g00 * g22 - g02 * g02) * inv;
        Ginv[5] = (g02 * g01 - g00 * g12) * inv;
        Ginv[6] = Ginv[2];
        Ginv[7] = Ginv[5];
        Ginv[8] = (g00 * g11 - g01 * g01) * inv;
    }
    __syncthreads();

    if (tid < 24) {                 // pinv[a][c] = sum_i A[i][a] * Ginv[i][c]
        const int a = tid / 3, c = tid % 3;
        double s = 0.0;
        for (int i = 0; i < 3; ++i)
            s += (double)Ab[i * NAXIS + a] * Ginv[i * 3 + c];
        w[a * 3 + c] = (float)s;
        float mn = 0.f, mx = 0.f;
        for (int i = 0; i < 3; ++i) {
            const float v = Ab[i * NAXIS + a];
            mn += fminf(v, 0.f);
            mx += fmaxf(v, 0.f);
        }
        const float invdx = 17.0f / (mx + EPS - mn);
        w[24 + a * 3 + c] = Ab[c * NAXIS + a] * invdx;   // uA
    }
    if (tid < NAXIS) {
        const int a = tid;
        float mn = 0.f, mx = 0.f;
        for (int c = 0; c < 3; ++c) {
            const float v = Ab[c * NAXIS + a];
            mn += fminf(v, 0.f);
            mx += fmaxf(v, 0.f);
        }
        const float range = mx + EPS - mn;
        const float invdx = 17.0f / range;
        w[48 + a] = -mn * invdx;                         // uoff
        float yf[NKNOTS + 2];
        yf[0] = mn;
        for (int k = 0; k < NKNOTS; ++k) yf[k + 1] = ysb[a * NKNOTS + k];
        yf[NKNOTS + 1] = mx;
        for (int s = 0; s < NSEG; ++s) {
            const float dy = yf[s + 1] - yf[s];
            // est(u) = dy*u + (yf[s+1] - (s+1)*dy)
            w[64 + (a * NSEG + s) * 2 + 0] = dy;
            w[64 + (a * NSEG + s) * 2 + 1] = yf[s + 1] - (float)(s + 1) * dy;
        }
    }
}

__device__ __forceinline__ float rfl(float x) {
    return __int_as_float(__builtin_amdgcn_readfirstlane(__float_as_int(x)));
}

__global__ __launch_bounds__(256) void spline_main(const float* __restrict__ raw,
                                                   const float* __restrict__ ws,
                                                   float* __restrict__ out,
                                                   int blocksPerBatch, int HW) {
    const int b   = blockIdx.x / blocksPerBatch;
    const int blk = blockIdx.x % blocksPerBatch;

    const float* w = ws + (size_t)b * WS_STRIDE;

    // block owns TILES consecutive 4KB tiles per color stream
    const size_t base0 = (size_t)b * 3 * HW + (size_t)blk * PXB + threadIdx.x * 4;

    // issue first tile's loads immediately — in flight during setup
    fv4 r4 = *(const fv4*)(raw + base0);
    fv4 g4 = *(const fv4*)(raw + base0 + HW);
    fv4 b4 = *(const fv4*)(raw + base0 + 2 * (size_t)HW);

    // wave-uniform per-batch coefficients -> SGPRs via readfirstlane.
    // 56 floats: pinv(24) | uA(24) | uoff(8); constant indices only.
    float cc[56];
    #pragma unroll
    for (int i = 0; i < 14; ++i) {
        const fv4 t = *(const fv4*)(w + 4 * i);
        cc[4 * i + 0] = rfl(t.x);
        cc[4 * i + 1] = rfl(t.y);
        cc[4 * i + 2] = rfl(t.z);
        cc[4 * i + 3] = rfl(t.w);
    }
    const float* cP = cc;        // pinv[a*3+c]
    const float* cA = cc + 24;   // uA[a*3+c]
    const float* cO = cc + 48;   // uoff[a]

    // only the per-lane-indexed segment table lives in LDS
    __shared__ float2 sseg[NAXIS * NSEG];
    {
        const float2* wseg = (const float2*)(w + 64);
        for (int i = threadIdx.x; i < NAXIS * NSEG; i += 256)
            sseg[i] = wseg[i];
    }
    __syncthreads();

    #pragma unroll
    for (int t = 0; t < TILES; ++t) {
        // software pipeline: issue next tile's loads before computing this one
        fv4 rn, gn, bn;
        if (t + 1 < TILES) {
            const size_t nb = base0 + (size_t)(t + 1) * 1024;
            rn = *(const fv4*)(raw + nb);
            gn = *(const fv4*)(raw + nb + HW);
            bn = *(const fv4*)(raw + nb + 2 * (size_t)HW);
        }

        fv4 o0, o1, o2;

        #pragma unroll
        for (int p = 0; p < 4; ++p) {
            const float rc = r4[p], gc = g4[p], bc = b4[p];
            float a0 = 0.f, a1 = 0.f, a2 = 0.f;
            #pragma unroll
            for (int a = 0; a < NAXIS; ++a) {
                const float u = fmaf(rc, cA[a * 3 + 0],
                                 fmaf(gc, cA[a * 3 + 1],
                                 fmaf(bc, cA[a * 3 + 2], cO[a])));
                const int idx = (int)fminf(fmaxf(u, 0.f), 16.0f);   // v_med3 + cvt
                const float2 ci = sseg[a * NSEG + idx];
                const float est = fmaf(ci.x, u, ci.y);
                a0 = fmaf(est, cP[a * 3 + 0], a0);
                a1 = fmaf(est, cP[a * 3 + 1], a1);
                a2 = fmaf(est, cP[a * 3 + 2], a2);
            }
            o0[p] = a0; o1[p] = a1; o2[p] = a2;
        }

        // nontemporal: output is never re-read; keep LLC for the input
        const size_t ob = base0 + (size_t)t * 1024;
        __builtin_nontemporal_store(o0, (fv4*)(out + ob));
        __builtin_nontemporal_store(o1, (fv4*)(out + ob + HW));
        __builtin_nontemporal_store(o2, (fv4*)(out + ob + 2 * (size_t)HW));

        r4 = rn; g4 = gn; b4 = bn;
    }
}

extern "C" void kernel_launch(void* const* d_in, const int* in_sizes, int n_in,
                              void* d_out, int out_size, void* d_ws, size_t ws_size,
                              hipStream_t stream) {
    const float* raw = (const float*)d_in[0];
    const float* ys  = (const float*)d_in[1];
    const float* A   = (const float*)d_in[2];
    float* out = (float*)d_out;
    float* ws  = (float*)d_ws;

    const int B  = in_sizes[2] / (3 * NAXIS);        // 8
    const int HW = in_sizes[0] / (B * 3);            // 1024*1024
    const int blocksPerBatch = HW / PXB;             // 256 for 1024x1024

    spline_prep<<<B, 64, 0, stream>>>(ys, A, ws);
    spline_main<<<B * blocksPerBatch, 256, 0, stream>>>(raw, ws, out, blocksPerBatch, HW);
}

// Round 4
// 176.146 us; speedup vs baseline: 1.0479x; 1.0479x over previous
//
#include <hip/hip_runtime.h>

#define EPS 1e-4f
#define NAXIS 8
#define NKNOTS 16      // interior knots; 18 total x-positions, 17 segments
#define NSEG 17
// per-batch workspace layout (floats), stride 384:
//  [0..24)    pinv[a*3+c]
//  [24..48)   uA[a*3+c]  = A[c][a] * invdx[a]   (projection straight into u-space)
//  [48..56)   uoff[a]    = -mins[a] * invdx[a]
//  [56..64)   pad
//  [64..336)  seg[a*17+s] as float2 {dy, icept}: est = dy*u + icept
#define WS_STRIDE 384

typedef float fv4 __attribute__((ext_vector_type(4)));   // native vector for nontemporal builtins

__global__ void spline_prep(const float* __restrict__ ys,
                            const float* __restrict__ A,
                            float* __restrict__ ws) {
    const int b = blockIdx.x;
    const float* Ab  = A  + (size_t)b * 3 * NAXIS;     // A[c*8+a]
    const float* ysb = ys + (size_t)b * NAXIS * NKNOTS;
    float* w = ws + (size_t)b * WS_STRIDE;
    __shared__ double Ginv[9];
    const int tid = threadIdx.x;

    if (tid == 0) {
        // G = A A^T (3x3, symmetric), fp64 for safety
        double G[9];
        for (int i = 0; i < 3; ++i)
            for (int j = 0; j < 3; ++j) {
                double s = 0.0;
                for (int a = 0; a < NAXIS; ++a)
                    s += (double)Ab[i * NAXIS + a] * (double)Ab[j * NAXIS + a];
                G[i * 3 + j] = s;
            }
        const double g00 = G[0], g01 = G[1], g02 = G[2];
        const double g11 = G[4], g12 = G[5], g22 = G[8];
        const double det = g00 * (g11 * g22 - g12 * g12)
                         - g01 * (g01 * g22 - g12 * g02)
                         + g02 * (g01 * g12 - g11 * g02);
        const double inv = 1.0 / det;
        Ginv[0] = (g11 * g22 - g12 * g12) * inv;
        Ginv[1] = (g02 * g12 - g01 * g22) * inv;
        Ginv[2] = (g01 * g12 - g02 * g11) * inv;
        Ginv[3] = Ginv[1];
        Ginv[4] = (g00 * g22 - g02 * g02) * inv;
        Ginv[5] = (g02 * g01 - g00 * g12) * inv;
        Ginv[6] = Ginv[2];
        Ginv[7] = Ginv[5];
        Ginv[8] = (g00 * g11 - g01 * g01) * inv;
    }
    __syncthreads();

    if (tid < 24) {                 // pinv[a][c] = sum_i A[i][a] * Ginv[i][c]
        const int a = tid / 3, c = tid % 3;
        double s = 0.0;
        for (int i = 0; i < 3; ++i)
            s += (double)Ab[i * NAXIS + a] * Ginv[i * 3 + c];
        w[a * 3 + c] = (float)s;
        float mn = 0.f, mx = 0.f;
        for (int i = 0; i < 3; ++i) {
            const float v = Ab[i * NAXIS + a];
            mn += fminf(v, 0.f);
            mx += fmaxf(v, 0.f);
        }
        const float invdx = 17.0f / (mx + EPS - mn);
        w[24 + a * 3 + c] = Ab[c * NAXIS + a] * invdx;   // uA
    }
    if (tid < NAXIS) {
        const int a = tid;
        float mn = 0.f, mx = 0.f;
        for (int c = 0; c < 3; ++c) {
            const float v = Ab[c * NAXIS + a];
            mn += fminf(v, 0.f);
            mx += fmaxf(v, 0.f);
        }
        const float range = mx + EPS - mn;
        const float invdx = 17.0f / range;
        w[48 + a] = -mn * invdx;                         // uoff
        float yf[NKNOTS + 2];
        yf[0] = mn;
        for (int k = 0; k < NKNOTS; ++k) yf[k + 1] = ysb[a * NKNOTS + k];
        yf[NKNOTS + 1] = mx;
        for (int s = 0; s < NSEG; ++s) {
            const float dy = yf[s + 1] - yf[s];
            // est(u) = dy*u + (yf[s+1] - (s+1)*dy)
            w[64 + (a * NSEG + s) * 2 + 0] = dy;
            w[64 + (a * NSEG + s) * 2 + 1] = yf[s + 1] - (float)(s + 1) * dy;
        }
    }
}

__device__ __forceinline__ float rfl(float x) {
    return __int_as_float(__builtin_amdgcn_readfirstlane(__float_as_int(x)));
}

__global__ __launch_bounds__(256) void spline_main(const float* __restrict__ raw,
                                                   const float* __restrict__ ws,
                                                   float* __restrict__ out,
                                                   int blocksPerBatch, int HW) {
    const int b    = blockIdx.x / blocksPerBatch;
    const int tile = blockIdx.x % blocksPerBatch;

    const float* w = ws + (size_t)b * WS_STRIDE;

    // nontemporal streaming loads: bypass L1 allocation — the 3 read + 3 write
    // streams sit at exactly 4 MB stride (HW = 2^20) and alias the same L1 sets.
    const size_t base = (size_t)b * 3 * HW + (size_t)tile * 1024 + threadIdx.x * 4;
    const fv4 r4 = __builtin_nontemporal_load((const fv4*)(raw + base));
    const fv4 g4 = __builtin_nontemporal_load((const fv4*)(raw + base + HW));
    const fv4 b4 = __builtin_nontemporal_load((const fv4*)(raw + base + 2 * (size_t)HW));

    // wave-uniform per-batch coefficients -> SGPRs via readfirstlane.
    // 56 floats: pinv(24) | uA(24) | uoff(8); constant indices only. (cached loads)
    float cc[56];
    #pragma unroll
    for (int i = 0; i < 14; ++i) {
        const fv4 t = *(const fv4*)(w + 4 * i);
        cc[4 * i + 0] = rfl(t.x);
        cc[4 * i + 1] = rfl(t.y);
        cc[4 * i + 2] = rfl(t.z);
        cc[4 * i + 3] = rfl(t.w);
    }
    const float* cP = cc;        // pinv[a*3+c]
    const float* cA = cc + 24;   // uA[a*3+c]
    const float* cO = cc + 48;   // uoff[a]

    // only the per-lane-indexed segment table lives in LDS
    __shared__ float2 sseg[NAXIS * NSEG];
    {
        const float2* wseg = (const float2*)(w + 64);
        for (int i = threadIdx.x; i < NAXIS * NSEG; i += 256)
            sseg[i] = wseg[i];
    }
    __syncthreads();

    fv4 o0, o1, o2;

    #pragma unroll
    for (int p = 0; p < 4; ++p) {
        const float rc = r4[p], gc = g4[p], bc = b4[p];
        float a0 = 0.f, a1 = 0.f, a2 = 0.f;
        #pragma unroll
        for (int a = 0; a < NAXIS; ++a) {
            const float u = fmaf(rc, cA[a * 3 + 0],
                             fmaf(gc, cA[a * 3 + 1],
                             fmaf(bc, cA[a * 3 + 2], cO[a])));
            const int idx = (int)fminf(fmaxf(u, 0.f), 16.0f);   // v_med3 + cvt
            const float2 ci = sseg[a * NSEG + idx];
            const float est = fmaf(ci.x, u, ci.y);
            a0 = fmaf(est, cP[a * 3 + 0], a0);
            a1 = fmaf(est, cP[a * 3 + 1], a1);
            a2 = fmaf(est, cP[a * 3 + 2], a2);
        }
        o0[p] = a0; o1[p] = a1; o2[p] = a2;
    }

    __builtin_nontemporal_store(o0, (fv4*)(out + base));
    __builtin_nontemporal_store(o1, (fv4*)(out + base + HW));
    __builtin_nontemporal_store(o2, (fv4*)(out + base + 2 * (size_t)HW));
}

extern "C" void kernel_launch(void* const* d_in, const int* in_sizes, int n_in,
                              void* d_out, int out_size, void* d_ws, size_t ws_size,
                              hipStream_t stream) {
    const float* raw = (const float*)d_in[0];
    const float* ys  = (const float*)d_in[1];
    const float* A   = (const float*)d_in[2];
    float* out = (float*)d_out;
    float* ws  = (float*)d_ws;

    const int B  = in_sizes[2] / (3 * NAXIS);        // 8
    const int HW = in_sizes[0] / (B * 3);            // 1024*1024
    const int blocksPerBatch = HW / 1024;            // 256 thr * 4 px

    spline_prep<<<B, 64, 0, stream>>>(ys, A, ws);
    spline_main<<<B * blocksPerBatch, 256, 0, stream>>>(raw, ws, out, blocksPerBatch, HW);
}